// Round 1
// baseline (683.944 us; speedup 1.0000x reference)
//
#include <hip/hip_runtime.h>

// GATConv single layer, fp32. N=50000 nodes, E=800000 edges (+N self loops),
// IN=128, HEADS=4, OUT=32 (HC=128 output channels).
//
// Pipeline (all on `stream`, implicit ordering):
//   memset out, denom
//   K1 gat_gemm : h = x@W (W in LDS), fused a_src/a_dst head-dots via shuffles
//   K2 gat_edge : w = exp(leakyrelu(a_src[s]+a_dst[d])); denom[d] += w (atomic)
//   K3 gat_agg  : out[d*128+j] += w * h[s*128+j]  (fp32 global atomics)
//   K4 gat_final: out = out/denom + bias
// No segment-max: logits are O(7) so exp() is safe in fp32 and
// exp(e)/sum(exp(e)) == exp(e-m)/sum(exp(e-m)) exactly in math.

constexpr int N_NODES = 50000;
constexpr int N_EDGES = 800000;
constexpr int E_TOT   = N_EDGES + N_NODES;  // 850000 incl. self loops
constexpr int IN_CH   = 128;
constexpr int HC      = 128;                // HEADS*OUT_CH
constexpr float NEG_SLOPE = 0.2f;

__global__ __launch_bounds__(256) void gat_gemm(
    const float* __restrict__ x, const float* __restrict__ W,
    const float* __restrict__ att_src, const float* __restrict__ att_dst,
    float* __restrict__ h, float* __restrict__ a_src, float* __restrict__ a_dst)
{
    __shared__ float Wl[IN_CH * HC];   // 64 KB -> 2 blocks/CU
    __shared__ float xs[8][IN_CH];
    const int tid = threadIdx.x;
    for (int i = tid * 4; i < IN_CH * HC; i += 256 * 4)
        *(float4*)&Wl[i] = *(const float4*)&W[i];

    const int c0   = (tid & 31) * 4;      // 4 consecutive output channels
    const int nl   = tid >> 5;            // 8 nodes per block-iteration
    const int head = (tid & 31) >> 3;     // c0/32
    const float4 asw = *(const float4*)&att_src[c0];
    const float4 adw = *(const float4*)&att_dst[c0];
    __syncthreads();

    for (int n0 = blockIdx.x * 8; n0 < N_NODES; n0 += gridDim.x * 8) {
        for (int i = tid; i < 8 * IN_CH; i += 256)
            xs[i >> 7][i & 127] = x[(size_t)(n0 + (i >> 7)) * IN_CH + (i & 127)];
        __syncthreads();

        const int n = n0 + nl;            // N_NODES % 8 == 0, no tail
        float4 acc = {0.f, 0.f, 0.f, 0.f};
        const float* xr = xs[nl];
        #pragma unroll 4
        for (int k = 0; k < IN_CH; ++k) {
            const float xv = xr[k];
            const float4 wv = *(const float4*)&Wl[k * HC + c0];
            acc.x += xv * wv.x; acc.y += xv * wv.y;
            acc.z += xv * wv.z; acc.w += xv * wv.w;
        }
        *(float4*)&h[(size_t)n * HC + c0] = acc;

        // per-head dots: reduce 8 lanes (32 channels / 4 per lane)
        float vs = acc.x*asw.x + acc.y*asw.y + acc.z*asw.z + acc.w*asw.w;
        float vd = acc.x*adw.x + acc.y*adw.y + acc.z*adw.z + acc.w*adw.w;
        vs += __shfl_xor(vs, 1); vd += __shfl_xor(vd, 1);
        vs += __shfl_xor(vs, 2); vd += __shfl_xor(vd, 2);
        vs += __shfl_xor(vs, 4); vd += __shfl_xor(vd, 4);
        if ((tid & 7) == 0) {
            a_src[n * 4 + head] = vs;
            a_dst[n * 4 + head] = vd;
        }
        __syncthreads();
    }
}

__global__ __launch_bounds__(256) void gat_edge(
    const int* __restrict__ esrc, const int* __restrict__ edst,
    const float* __restrict__ a_src, const float* __restrict__ a_dst,
    float* __restrict__ denom, float* __restrict__ wbuf)
{
    const int e = blockIdx.x * 256 + threadIdx.x;
    if (e >= E_TOT) return;
    int s, d;
    if (e < N_EDGES) { s = esrc[e]; d = edst[e]; }
    else             { s = e - N_EDGES; d = s; }     // self loop
    const float4 as = *(const float4*)&a_src[s * 4];
    const float4 ad = *(const float4*)&a_dst[d * 4];
    float4 w; float t;
    t = as.x + ad.x; t = t > 0.f ? t : NEG_SLOPE * t; w.x = __expf(t);
    t = as.y + ad.y; t = t > 0.f ? t : NEG_SLOPE * t; w.y = __expf(t);
    t = as.z + ad.z; t = t > 0.f ? t : NEG_SLOPE * t; w.z = __expf(t);
    t = as.w + ad.w; t = t > 0.f ? t : NEG_SLOPE * t; w.w = __expf(t);
    *(float4*)&wbuf[(size_t)e * 4] = w;
    atomicAdd(&denom[d * 4 + 0], w.x);
    atomicAdd(&denom[d * 4 + 1], w.y);
    atomicAdd(&denom[d * 4 + 2], w.z);
    atomicAdd(&denom[d * 4 + 3], w.w);
}

__global__ __launch_bounds__(256) void gat_agg(
    const int* __restrict__ esrc, const int* __restrict__ edst,
    const float* __restrict__ h, const float* __restrict__ wbuf,
    float* __restrict__ out)
{
    const int idx = blockIdx.x * 256 + threadIdx.x;   // < 108.8M, fits int
    if (idx >= E_TOT * 128) return;
    const int e = idx >> 7;
    const int j = idx & 127;
    int s, d;
    if (e < N_EDGES) { s = esrc[e]; d = edst[e]; }
    else             { s = e - N_EDGES; d = s; }
    const float wv = wbuf[e * 4 + (j >> 5)];
    atomicAdd(&out[(size_t)d * 128 + j], wv * h[(size_t)s * 128 + j]);
}

__global__ __launch_bounds__(256) void gat_final(
    const float* __restrict__ denom, const float* __restrict__ bias,
    float* __restrict__ out)
{
    const int idx = blockIdx.x * 256 + threadIdx.x;
    if (idx >= N_NODES * 128) return;
    const int n = idx >> 7, j = idx & 127;
    out[idx] = out[idx] / denom[n * 4 + (j >> 5)] + bias[j];
}

extern "C" void kernel_launch(void* const* d_in, const int* in_sizes, int n_in,
                              void* d_out, int out_size, void* d_ws, size_t ws_size,
                              hipStream_t stream) {
    const float* x       = (const float*)d_in[0];
    const int*   ei      = (const int*)  d_in[1];   // [2, E]: row0=src, row1=dst
    const float* W       = (const float*)d_in[2];
    const float* att_src = (const float*)d_in[3];
    const float* att_dst = (const float*)d_in[4];
    const float* bias    = (const float*)d_in[5];
    float* out = (float*)d_out;

    // workspace layout (floats): h | a_src | a_dst | denom | wbuf  (~41.6 MB)
    float* ws     = (float*)d_ws;
    float* h      = ws;                        // N*128
    float* a_src  = h     + (size_t)N_NODES * HC;
    float* a_dst  = a_src + (size_t)N_NODES * 4;
    float* denom  = a_dst + (size_t)N_NODES * 4;
    float* wbuf   = denom + (size_t)N_NODES * 4;   // E_TOT*4

    const int* esrc = ei;
    const int* edst = ei + N_EDGES;

    hipMemsetAsync(out,   0, (size_t)N_NODES * HC * sizeof(float), stream);
    hipMemsetAsync(denom, 0, (size_t)N_NODES * 4  * sizeof(float), stream);

    gat_gemm<<<1024, 256, 0, stream>>>(x, W, att_src, att_dst, h, a_src, a_dst);
    gat_edge<<<(E_TOT + 255) / 256, 256, 0, stream>>>(esrc, edst, a_src, a_dst, denom, wbuf);
    gat_agg<<<(E_TOT * 128 + 255) / 256, 256, 0, stream>>>(esrc, edst, h, wbuf, out);
    gat_final<<<(N_NODES * HC + 255) / 256, 256, 0, stream>>>(denom, bias, out);
}

// Round 2
// 302.186 us; speedup vs baseline: 2.2633x; 2.2633x over previous
//
#include <hip/hip_runtime.h>

// GATConv single layer, fp32. N=50000 nodes, E=800000 edges (+N self loops),
// IN=128, HEADS=4, OUT=32 (HC=128 output channels).
//
// R2: CSR-by-dst gather replaces the 108.8M-atomic scatter of R1.
// Pipeline (all on `stream`):
//   K1 init_deg    : deg=1, cursor=1 (self loop counted)
//   K2 hist        : deg[dst]++ over E edges (int atomics, ~16/address)
//   K3-5 scan      : row_start = exclusive_scan(deg)  (block scan + bsum + add;
//                    scan_add also plants self-loop src in slot 0 of each row)
//   K6 scatter     : csr_src[row_start[d] + cursor[d]++] = src
//   K7 gat_gemm    : h = x@W (W in LDS), fused a_src/a_dst head-dots
//   K8 gat_agg_csr : one WAVE per dst node; batch-load row's srcs (1 coalesced
//                    load), shfl-broadcast; w=exp(leakyrelu(..)) on the fly;
//                    denom = running sum in-register; fused /denom + bias.
// No segment-max: logits are O(7), exp() safe in fp32; exp(e)/sum(exp(e)) is
// mathematically identical to the max-subtracted form.

constexpr int N_NODES = 50000;
constexpr int N_EDGES = 800000;
constexpr int E_TOT   = N_EDGES + N_NODES;  // 850000 incl. self loops
constexpr int IN_CH   = 128;
constexpr int HC      = 128;                // HEADS*OUT_CH
constexpr float NEG_SLOPE = 0.2f;
constexpr int SCAN_BLOCKS = (N_NODES + 255) / 256;  // 196

__global__ __launch_bounds__(256) void init_deg(int* __restrict__ deg, int* __restrict__ cursor) {
    const int i = blockIdx.x * 256 + threadIdx.x;
    if (i < N_NODES) { deg[i] = 1; cursor[i] = 1; }  // slot 0 = self loop
}

__global__ __launch_bounds__(256) void hist(const int* __restrict__ edst, int* __restrict__ deg) {
    const int e = blockIdx.x * 256 + threadIdx.x;
    if (e < N_EDGES) atomicAdd(&deg[edst[e]], 1);
}

__global__ __launch_bounds__(256) void scan_blocks(const int* __restrict__ deg,
                                                   int* __restrict__ row_start,
                                                   int* __restrict__ bsum) {
    __shared__ int sm[256];
    const int tid = threadIdx.x;
    const int i = blockIdx.x * 256 + tid;
    const int v = (i < N_NODES) ? deg[i] : 0;
    sm[tid] = v; __syncthreads();
    for (int off = 1; off < 256; off <<= 1) {
        const int t = (tid >= off) ? sm[tid - off] : 0;
        __syncthreads();
        sm[tid] += t;
        __syncthreads();
    }
    if (i < N_NODES) row_start[i] = sm[tid] - v;     // exclusive within block
    if (tid == 255) bsum[blockIdx.x] = sm[255];
}

__global__ __launch_bounds__(256) void scan_bsum(int* __restrict__ bsum) {
    __shared__ int sm[256];
    const int tid = threadIdx.x;
    const int v = (tid < SCAN_BLOCKS) ? bsum[tid] : 0;
    sm[tid] = v; __syncthreads();
    for (int off = 1; off < 256; off <<= 1) {
        const int t = (tid >= off) ? sm[tid - off] : 0;
        __syncthreads();
        sm[tid] += t;
        __syncthreads();
    }
    if (tid < SCAN_BLOCKS) bsum[tid] = sm[tid] - v;  // exclusive
}

__global__ __launch_bounds__(256) void scan_add(int* __restrict__ row_start,
                                                const int* __restrict__ bsum,
                                                int* __restrict__ csr_src) {
    const int i = blockIdx.x * 256 + threadIdx.x;
    if (i < N_NODES) {
        const int r = row_start[i] + bsum[blockIdx.x];
        row_start[i] = r;
        csr_src[r] = i;                              // self loop in slot 0
    }
    if (i == 0) row_start[N_NODES] = E_TOT;
}

__global__ __launch_bounds__(256) void scatter(const int* __restrict__ esrc,
                                               const int* __restrict__ edst,
                                               const int* __restrict__ row_start,
                                               int* __restrict__ cursor,
                                               int* __restrict__ csr_src) {
    const int e = blockIdx.x * 256 + threadIdx.x;
    if (e >= N_EDGES) return;
    const int d = edst[e];
    const int pos = row_start[d] + atomicAdd(&cursor[d], 1);
    csr_src[pos] = esrc[e];
}

__global__ __launch_bounds__(256) void gat_gemm(
    const float* __restrict__ x, const float* __restrict__ W,
    const float* __restrict__ att_src, const float* __restrict__ att_dst,
    float* __restrict__ h, float* __restrict__ a_src, float* __restrict__ a_dst)
{
    __shared__ float Wl[IN_CH * HC];   // 64 KB -> 2 blocks/CU
    __shared__ float xs[8][IN_CH];
    const int tid = threadIdx.x;
    for (int i = tid * 4; i < IN_CH * HC; i += 256 * 4)
        *(float4*)&Wl[i] = *(const float4*)&W[i];

    const int c0   = (tid & 31) * 4;      // 4 consecutive output channels
    const int nl   = tid >> 5;            // 8 nodes per block-iteration
    const int head = (tid & 31) >> 3;     // c0/32
    const float4 asw = *(const float4*)&att_src[c0];
    const float4 adw = *(const float4*)&att_dst[c0];
    __syncthreads();

    for (int n0 = blockIdx.x * 8; n0 < N_NODES; n0 += gridDim.x * 8) {
        for (int i = tid; i < 8 * IN_CH; i += 256)
            xs[i >> 7][i & 127] = x[(size_t)(n0 + (i >> 7)) * IN_CH + (i & 127)];
        __syncthreads();

        const int n = n0 + nl;            // N_NODES % 8 == 0, no tail
        float4 acc = {0.f, 0.f, 0.f, 0.f};
        const float* xr = xs[nl];
        #pragma unroll 4
        for (int k = 0; k < IN_CH; ++k) {
            const float xv = xr[k];
            const float4 wv = *(const float4*)&Wl[k * HC + c0];
            acc.x += xv * wv.x; acc.y += xv * wv.y;
            acc.z += xv * wv.z; acc.w += xv * wv.w;
        }
        *(float4*)&h[(size_t)n * HC + c0] = acc;

        // per-head dots: reduce 8 lanes (32 channels / 4 per lane)
        float vs = acc.x*asw.x + acc.y*asw.y + acc.z*asw.z + acc.w*asw.w;
        float vd = acc.x*adw.x + acc.y*adw.y + acc.z*adw.z + acc.w*adw.w;
        vs += __shfl_xor(vs, 1); vd += __shfl_xor(vd, 1);
        vs += __shfl_xor(vs, 2); vd += __shfl_xor(vd, 2);
        vs += __shfl_xor(vs, 4); vd += __shfl_xor(vd, 4);
        if ((tid & 7) == 0) {
            a_src[n * 4 + head] = vs;
            a_dst[n * 4 + head] = vd;
        }
        __syncthreads();
    }
}

__global__ __launch_bounds__(256) void gat_agg_csr(
    const int* __restrict__ row_start, const int* __restrict__ csr_src,
    const float* __restrict__ h, const float* __restrict__ a_src,
    const float* __restrict__ a_dst, const float* __restrict__ bias,
    float* __restrict__ out)
{
    const int node = blockIdx.x * 4 + (threadIdx.x >> 6);
    if (node >= N_NODES) return;
    const int lane = threadIdx.x & 63;
    const int head = lane >> 4;                       // ch = lane*2 -> head = lane/16
    const float ad = a_dst[node * 4 + head];
    const int p0 = row_start[node], p1 = row_start[node + 1];

    float2 acc = {0.f, 0.f};
    float dsum = 0.f;
    for (int base = p0; base < p1; base += 64) {
        int m = p1 - base; if (m > 64) m = 64;
        const int sv = (lane < m) ? csr_src[base + lane] : 0;  // 1 coalesced load
        for (int k = 0; k < m; ++k) {
            const int s = __shfl(sv, k);
            float t = a_src[s * 4 + head] + ad;
            t = t > 0.f ? t : NEG_SLOPE * t;
            const float w = __expf(t);
            const float2 hv = *(const float2*)&h[(size_t)s * HC + lane * 2];
            acc.x += w * hv.x; acc.y += w * hv.y; dsum += w;
        }
    }
    const float inv = 1.f / dsum;                     // dsum >= exp(self) > 0
    const int j = lane * 2;
    out[(size_t)node * HC + j]     = acc.x * inv + bias[j];
    out[(size_t)node * HC + j + 1] = acc.y * inv + bias[j + 1];
}

extern "C" void kernel_launch(void* const* d_in, const int* in_sizes, int n_in,
                              void* d_out, int out_size, void* d_ws, size_t ws_size,
                              hipStream_t stream) {
    const float* x       = (const float*)d_in[0];
    const int*   ei      = (const int*)  d_in[1];   // [2, E]: row0=src, row1=dst
    const float* W       = (const float*)d_in[2];
    const float* att_src = (const float*)d_in[3];
    const float* att_dst = (const float*)d_in[4];
    const float* bias    = (const float*)d_in[5];
    float* out = (float*)d_out;

    // workspace layout (~31.2 MB): h | a_src | a_dst | csr_src | row_start | deg | cursor | bsum
    float* ws       = (float*)d_ws;
    float* h        = ws;                                   // N*128 f
    float* a_src    = h     + (size_t)N_NODES * HC;         // N*4 f
    float* a_dst    = a_src + (size_t)N_NODES * 4;          // N*4 f
    int*   csr_src  = (int*)(a_dst + (size_t)N_NODES * 4);  // E_TOT ints
    int*   row_st   = csr_src + E_TOT;                      // N+1 (pad 4)
    int*   deg      = row_st + N_NODES + 4;                 // N
    int*   cursor   = deg + N_NODES;                        // N
    int*   bsum     = cursor + N_NODES;                     // 256

    const int* esrc = ei;
    const int* edst = ei + N_EDGES;

    init_deg   <<<SCAN_BLOCKS, 256, 0, stream>>>(deg, cursor);
    hist       <<<(N_EDGES + 255) / 256, 256, 0, stream>>>(edst, deg);
    scan_blocks<<<SCAN_BLOCKS, 256, 0, stream>>>(deg, row_st, bsum);
    scan_bsum  <<<1, 256, 0, stream>>>(bsum);
    scan_add   <<<SCAN_BLOCKS, 256, 0, stream>>>(row_st, bsum, csr_src);
    scatter    <<<(N_EDGES + 255) / 256, 256, 0, stream>>>(esrc, edst, row_st, cursor, csr_src);
    gat_gemm   <<<1024, 256, 0, stream>>>(x, W, att_src, att_dst, h, a_src, a_dst);
    gat_agg_csr<<<(N_NODES + 3) / 4, 256, 0, stream>>>(row_st, csr_src, h, a_src, a_dst, bias, out);
}

// Round 3
// 263.989 us; speedup vs baseline: 2.5908x; 1.1447x over previous
//
#include <hip/hip_runtime.h>

// GATConv single layer. N=50000, E=800000 (+N self loops), IN=128, H*C=128.
//
// R3: bf16 MFMA GEMM (register-resident B frags) + bf16 h in the CSR gather.
// Pipeline (all on `stream`):
//   memset deg|cursor (adjacent, one memset)
//   K1 hist        : deg[dst]++ (self loop +1 folded into scan)
//   K2-4 scan      : row_start = exclusive_scan(deg+1); plants self-loop slot 0
//   K5 scatter     : csr_src[row_start[d] + 1 + cursor[d]++] = src
//   K6 cast_x      : x fp32 -> bf16 bits
//   K7 cast_w      : W[k][n] fp32 -> Wt[n][k] bf16 bits (transposed for B-frag)
//   K8 gat_gemm    : h_bf16 = x@W via v_mfma_f32_16x16x32_bf16, fp32 accum
//   K9 gat_att     : a_src/a_dst = per-head dots of h rows (wave per node)
//   K10 gat_agg_csr: wave per dst node; batch srcs, shfl-broadcast; w=exp(
//                    leakyrelu(..)) on the fly; denom in-register; /denom+bias.
// No segment-max: logits are O(7), exp() safe in fp32; exp(e)/sum == softmax.

constexpr int N_NODES = 50000;
constexpr int N_EDGES = 800000;
constexpr int E_TOT   = N_EDGES + N_NODES;  // 850000
constexpr int HC      = 128;
constexpr float NEG_SLOPE = 0.2f;
constexpr int SCAN_BLOCKS = (N_NODES + 255) / 256;  // 196
constexpr int M_TILES = N_NODES / 16;               // 3125

typedef short short8 __attribute__((ext_vector_type(8)));
typedef float f32x4  __attribute__((ext_vector_type(4)));

__device__ inline unsigned short f2bf(float f) {   // RTNE
    unsigned int u = __float_as_uint(f);
    u += 0x7FFF + ((u >> 16) & 1);
    return (unsigned short)(u >> 16);
}
__device__ inline float bf2f(unsigned short b) {
    return __uint_as_float((unsigned int)b << 16);
}

// ---------------- CSR build ----------------

__global__ __launch_bounds__(256) void hist(const int* __restrict__ edst, int* __restrict__ deg) {
    const int e = blockIdx.x * 256 + threadIdx.x;
    if (e < N_EDGES) atomicAdd(&deg[edst[e]], 1);
}

__global__ __launch_bounds__(256) void scan_blocks(const int* __restrict__ deg,
                                                   int* __restrict__ row_start,
                                                   int* __restrict__ bsum) {
    __shared__ int sm[256];
    const int tid = threadIdx.x;
    const int i = blockIdx.x * 256 + tid;
    const int v = (i < N_NODES) ? deg[i] + 1 : 0;    // +1 = self loop
    sm[tid] = v; __syncthreads();
    for (int off = 1; off < 256; off <<= 1) {
        const int t = (tid >= off) ? sm[tid - off] : 0;
        __syncthreads();
        sm[tid] += t;
        __syncthreads();
    }
    if (i < N_NODES) row_start[i] = sm[tid] - v;
    if (tid == 255) bsum[blockIdx.x] = sm[255];
}

__global__ __launch_bounds__(256) void scan_bsum(int* __restrict__ bsum) {
    __shared__ int sm[256];
    const int tid = threadIdx.x;
    const int v = (tid < SCAN_BLOCKS) ? bsum[tid] : 0;
    sm[tid] = v; __syncthreads();
    for (int off = 1; off < 256; off <<= 1) {
        const int t = (tid >= off) ? sm[tid - off] : 0;
        __syncthreads();
        sm[tid] += t;
        __syncthreads();
    }
    if (tid < SCAN_BLOCKS) bsum[tid] = sm[tid] - v;
}

__global__ __launch_bounds__(256) void scan_add(int* __restrict__ row_start,
                                                const int* __restrict__ bsum,
                                                int* __restrict__ csr_src) {
    const int i = blockIdx.x * 256 + threadIdx.x;
    if (i < N_NODES) {
        const int r = row_start[i] + bsum[blockIdx.x];
        row_start[i] = r;
        csr_src[r] = i;                              // self loop in slot 0
    }
    if (i == 0) row_start[N_NODES] = E_TOT;
}

__global__ __launch_bounds__(256) void scatter(const int* __restrict__ esrc,
                                               const int* __restrict__ edst,
                                               const int* __restrict__ row_start,
                                               int* __restrict__ cursor,
                                               int* __restrict__ csr_src) {
    const int e = blockIdx.x * 256 + threadIdx.x;
    if (e >= N_EDGES) return;
    const int d = edst[e];
    const int pos = row_start[d] + 1 + atomicAdd(&cursor[d], 1);
    csr_src[pos] = esrc[e];
}

// ---------------- casts ----------------

__global__ __launch_bounds__(256) void cast_x(const float4* __restrict__ x4,
                                              unsigned short* __restrict__ xb) {
    const int i = blockIdx.x * 256 + threadIdx.x;
    if (i >= N_NODES * HC / 4) return;
    const float4 v = x4[i];
    ushort4 o = { f2bf(v.x), f2bf(v.y), f2bf(v.z), f2bf(v.w) };
    *(ushort4*)&xb[(size_t)i * 4] = o;
}

__global__ __launch_bounds__(256) void cast_w(const float* __restrict__ W,
                                              unsigned short* __restrict__ wtb) {
    const int i = blockIdx.x * 256 + threadIdx.x;   // i = n*128 + k
    if (i >= 128 * 128) return;
    const int n = i >> 7, k = i & 127;
    wtb[i] = f2bf(W[k * 128 + n]);                  // Wt[n][k] = W[k][n]
}

// ---------------- GEMM: h = x @ W  (bf16 in, fp32 accum, bf16 out) ---------

__global__ __launch_bounds__(256) void gat_gemm(
    const unsigned short* __restrict__ xb,   // [N,128] bf16
    const unsigned short* __restrict__ wtb,  // [n:128][k:128] bf16 (B^T layout)
    unsigned short* __restrict__ hb)         // [N,128] bf16
{
    const int wave = threadIdx.x >> 6;
    const int lane = threadIdx.x & 63;
    const int n0   = (wave & 1) * 64;        // n-strip per wave
    const int l15  = lane & 15;
    const int quad = lane >> 4;

    // B fragments, loaded once: 4 n-tiles x 4 k-steps, 16 B/lane each.
    // B[k=ks*32+quad*8+j][n=n0+16t+l15] = Wt[n][k]  (k contiguous per lane)
    short8 bfrag[4][4];
    #pragma unroll
    for (int t = 0; t < 4; ++t)
        #pragma unroll
        for (int ks = 0; ks < 4; ++ks)
            bfrag[t][ks] = *(const short8*)&wtb[(n0 + t * 16 + l15) * 128 + ks * 32 + quad * 8];

    for (int mt = blockIdx.x * 2 + (wave >> 1); mt < M_TILES; mt += gridDim.x * 2) {
        const int m0 = mt * 16;
        short8 afrag[4];                     // A[m=m0+l15][k=ks*32+quad*8+j]
        #pragma unroll
        for (int ks = 0; ks < 4; ++ks)
            afrag[ks] = *(const short8*)&xb[(m0 + l15) * 128 + ks * 32 + quad * 8];

        f32x4 acc[4];
        #pragma unroll
        for (int t = 0; t < 4; ++t) acc[t] = (f32x4){0.f, 0.f, 0.f, 0.f};

        #pragma unroll
        for (int ks = 0; ks < 4; ++ks)
            #pragma unroll
            for (int t = 0; t < 4; ++t)
                acc[t] = __builtin_amdgcn_mfma_f32_16x16x32_bf16(afrag[ks], bfrag[t][ks], acc[t], 0, 0, 0);

        // C/D: col = l15 (+16t), row = quad*4 + r
        #pragma unroll
        for (int t = 0; t < 4; ++t)
            #pragma unroll
            for (int r = 0; r < 4; ++r)
                hb[(m0 + quad * 4 + r) * 128 + n0 + t * 16 + l15] = f2bf(acc[t][r]);
    }
}

// ---------------- per-head attention dots ----------------

__global__ __launch_bounds__(256) void gat_att(
    const unsigned short* __restrict__ hb,
    const float* __restrict__ att_src, const float* __restrict__ att_dst,
    float* __restrict__ a_src, float* __restrict__ a_dst)
{
    const int node = blockIdx.x * 4 + (threadIdx.x >> 6);
    const int lane = threadIdx.x & 63;
    const int head = lane >> 4;
    const int cw   = (lane & 15) * 2;        // channel pair within head
    const ushort2 hv = *(const ushort2*)&hb[node * 128 + lane * 2];
    const float hx = bf2f(hv.x), hy = bf2f(hv.y);
    const float2 as = *(const float2*)&att_src[head * 32 + cw];
    const float2 ad = *(const float2*)&att_dst[head * 32 + cw];
    float vs = hx * as.x + hy * as.y;
    float vd = hx * ad.x + hy * ad.y;
    vs += __shfl_xor(vs, 1); vd += __shfl_xor(vd, 1);
    vs += __shfl_xor(vs, 2); vd += __shfl_xor(vd, 2);
    vs += __shfl_xor(vs, 4); vd += __shfl_xor(vd, 4);
    vs += __shfl_xor(vs, 8); vd += __shfl_xor(vd, 8);
    if ((lane & 15) == 0) {
        a_src[node * 4 + head] = vs;
        a_dst[node * 4 + head] = vd;
    }
}

// ---------------- aggregation: wave per dst node ----------------

__global__ __launch_bounds__(256) void gat_agg_csr(
    const int* __restrict__ row_start, const int* __restrict__ csr_src,
    const unsigned short* __restrict__ hb, const float* __restrict__ a_src,
    const float* __restrict__ a_dst, const float* __restrict__ bias,
    float* __restrict__ out)
{
    const int node = blockIdx.x * 4 + (threadIdx.x >> 6);
    if (node >= N_NODES) return;
    const int lane = threadIdx.x & 63;
    const int head = lane >> 4;              // ch = lane*2 -> head = lane/16
    const float ad = a_dst[node * 4 + head];
    const int p0 = row_start[node], p1 = row_start[node + 1];

    float2 acc = {0.f, 0.f};
    float dsum = 0.f;
    for (int base = p0; base < p1; base += 64) {
        int m = p1 - base; if (m > 64) m = 64;
        const int sv = (lane < m) ? csr_src[base + lane] : 0;  // coalesced batch
        #pragma unroll 4
        for (int k = 0; k < m; ++k) {
            const int s = __shfl(sv, k);
            float t = a_src[s * 4 + head] + ad;
            t = t > 0.f ? t : NEG_SLOPE * t;
            const float w = __expf(t);
            const ushort2 hv = *(const ushort2*)&hb[s * 128 + lane * 2];
            acc.x += w * bf2f(hv.x);
            acc.y += w * bf2f(hv.y);
            dsum += w;
        }
    }
    const float inv = 1.f / dsum;            // dsum >= exp(self) > 0
    const int j = lane * 2;
    out[(size_t)node * HC + j]     = acc.x * inv + bias[j];
    out[(size_t)node * HC + j + 1] = acc.y * inv + bias[j + 1];
}

extern "C" void kernel_launch(void* const* d_in, const int* in_sizes, int n_in,
                              void* d_out, int out_size, void* d_ws, size_t ws_size,
                              hipStream_t stream) {
    const float* x       = (const float*)d_in[0];
    const int*   ei      = (const int*)  d_in[1];   // [2,E]: row0=src, row1=dst
    const float* W       = (const float*)d_in[2];
    const float* att_src = (const float*)d_in[3];
    const float* att_dst = (const float*)d_in[4];
    const float* bias    = (const float*)d_in[5];
    float* out = (float*)d_out;

    // ws layout: hb | xb | wtb | a_src | a_dst | csr_src | row_st | deg,cursor | bsum
    char* p = (char*)d_ws;
    unsigned short* hb  = (unsigned short*)p; p += (size_t)N_NODES * HC * 2;  // 12.8 MB
    unsigned short* xb  = (unsigned short*)p; p += (size_t)N_NODES * HC * 2;  // 12.8 MB
    unsigned short* wtb = (unsigned short*)p; p += 128 * 128 * 2;             // 32 KB
    float* a_src = (float*)p; p += (size_t)N_NODES * 4 * 4;                   // 800 KB
    float* a_dst = (float*)p; p += (size_t)N_NODES * 4 * 4;
    int* csr_src = (int*)p;   p += (size_t)E_TOT * 4;                         // 3.4 MB
    int* row_st  = (int*)p;   p += (N_NODES + 4) * 4;
    int* deg     = (int*)p;   p += N_NODES * 4;   // deg,cursor adjacent:
    int* cursor  = (int*)p;   p += N_NODES * 4;   // one memset covers both
    int* bsum    = (int*)p;

    const int* esrc = ei;
    const int* edst = ei + N_EDGES;

    hipMemsetAsync(deg, 0, (size_t)N_NODES * 2 * sizeof(int), stream);

    hist       <<<(N_EDGES + 255) / 256, 256, 0, stream>>>(edst, deg);
    scan_blocks<<<SCAN_BLOCKS, 256, 0, stream>>>(deg, row_st, bsum);
    scan_bsum  <<<1, 256, 0, stream>>>(bsum);
    scan_add   <<<SCAN_BLOCKS, 256, 0, stream>>>(row_st, bsum, csr_src);
    scatter    <<<(N_EDGES + 255) / 256, 256, 0, stream>>>(esrc, edst, row_st, cursor, csr_src);

    cast_x     <<<(N_NODES * HC / 4 + 255) / 256, 256, 0, stream>>>((const float4*)x, xb);
    cast_w     <<<64, 256, 0, stream>>>(W, wtb);
    gat_gemm   <<<512, 256, 0, stream>>>(xb, wtb, hb);
    gat_att    <<<N_NODES / 4, 256, 0, stream>>>(hb, att_src, att_dst, a_src, a_dst);
    gat_agg_csr<<<(N_NODES + 3) / 4, 256, 0, stream>>>(row_st, csr_src, hb, a_src, a_dst, bias, out);
}

// Round 4
// 198.921 us; speedup vs baseline: 3.4383x; 1.3271x over previous
//
#include <hip/hip_runtime.h>

// GATConv single layer. N=50000, E=800000 (+N self loops), IN=128, H*C=128.
//
// R4: agg with per-batch LDS weight table + 2 edges in flight; cast_x and
// gat_att fused into the MFMA GEMM; atomic-free scatter via ppos.
// Pipeline (all on `stream`):
//   memset deg
//   K1 hist      : ppos[e] = deg[dst]++            (the only atomic pass)
//   K2-4 scan    : row_start = exclusive_scan(deg+1); plants self-loop slot 0
//   K5 scatter   : csr_src[row_start[d] + 1 + ppos[e]] = src   (no atomics)
//   K6 cast_w    : W[k][n] fp32 -> Wt[n][k] bf16 (B-frag layout)
//   K7 gat_gemm  : h_bf16 = x@W via v_mfma_f32_16x16x32_bf16 (x converted
//                  in-register); epilogue computes a_src/a_dst from fp32 acc
//   K8 gat_agg   : wave per dst node; batch loads 64 srcs coalesced, one lane
//                  per edge precomputes all 4 head weights (4 exp/lane) into
//                  LDS; two half-waves process 2 edges in flight, 4 ch/lane;
//                  denom in-register; fused /denom + bias, float4 stores.
// No segment-max: logits are O(7), exp() safe in fp32; exp(e)/sum == softmax.

constexpr int N_NODES = 50000;
constexpr int N_EDGES = 800000;
constexpr int E_TOT   = N_EDGES + N_NODES;  // 850000
constexpr int HC      = 128;
constexpr float NEG_SLOPE = 0.2f;
constexpr int SCAN_BLOCKS = (N_NODES + 255) / 256;  // 196
constexpr int M_TILES = N_NODES / 16;               // 3125

typedef short short8 __attribute__((ext_vector_type(8)));
typedef float f32x4  __attribute__((ext_vector_type(4)));

__device__ inline unsigned short f2bf(float f) {   // RTNE
    unsigned int u = __float_as_uint(f);
    u += 0x7FFF + ((u >> 16) & 1);
    return (unsigned short)(u >> 16);
}

// ---------------- CSR build ----------------

__global__ __launch_bounds__(256) void hist(const int* __restrict__ edst,
                                            int* __restrict__ deg,
                                            int* __restrict__ ppos) {
    const int e = blockIdx.x * 256 + threadIdx.x;
    if (e < N_EDGES) ppos[e] = atomicAdd(&deg[edst[e]], 1);
}

__global__ __launch_bounds__(256) void scan_blocks(const int* __restrict__ deg,
                                                   int* __restrict__ row_start,
                                                   int* __restrict__ bsum) {
    __shared__ int sm[256];
    const int tid = threadIdx.x;
    const int i = blockIdx.x * 256 + tid;
    const int v = (i < N_NODES) ? deg[i] + 1 : 0;    // +1 = self loop
    sm[tid] = v; __syncthreads();
    for (int off = 1; off < 256; off <<= 1) {
        const int t = (tid >= off) ? sm[tid - off] : 0;
        __syncthreads();
        sm[tid] += t;
        __syncthreads();
    }
    if (i < N_NODES) row_start[i] = sm[tid] - v;
    if (tid == 255) bsum[blockIdx.x] = sm[255];
}

__global__ __launch_bounds__(256) void scan_bsum(int* __restrict__ bsum) {
    __shared__ int sm[256];
    const int tid = threadIdx.x;
    const int v = (tid < SCAN_BLOCKS) ? bsum[tid] : 0;
    sm[tid] = v; __syncthreads();
    for (int off = 1; off < 256; off <<= 1) {
        const int t = (tid >= off) ? sm[tid - off] : 0;
        __syncthreads();
        sm[tid] += t;
        __syncthreads();
    }
    if (tid < SCAN_BLOCKS) bsum[tid] = sm[tid] - v;
}

__global__ __launch_bounds__(256) void scan_add(int* __restrict__ row_start,
                                                const int* __restrict__ bsum,
                                                int* __restrict__ csr_src) {
    const int i = blockIdx.x * 256 + threadIdx.x;
    if (i < N_NODES) {
        const int r = row_start[i] + bsum[blockIdx.x];
        row_start[i] = r;
        csr_src[r] = i;                              // self loop in slot 0
    }
    if (i == 0) row_start[N_NODES] = E_TOT;
}

__global__ __launch_bounds__(256) void scatter(const int* __restrict__ esrc,
                                               const int* __restrict__ edst,
                                               const int* __restrict__ row_start,
                                               const int* __restrict__ ppos,
                                               int* __restrict__ csr_src) {
    const int e = blockIdx.x * 256 + threadIdx.x;
    if (e >= N_EDGES) return;
    csr_src[row_start[edst[e]] + 1 + ppos[e]] = esrc[e];
}

// ---------------- W transpose+cast ----------------

__global__ __launch_bounds__(256) void cast_w(const float* __restrict__ W,
                                              unsigned short* __restrict__ wtb) {
    const int i = blockIdx.x * 256 + threadIdx.x;   // i = n*128 + k
    if (i >= 128 * 128) return;
    const int n = i >> 7, k = i & 127;
    wtb[i] = f2bf(W[k * 128 + n]);                  // Wt[n][k] = W[k][n]
}

// ------- GEMM: h = x@W (in-reg fp32->bf16), fused a_src/a_dst epilogue -----

__global__ __launch_bounds__(256) void gat_gemm(
    const float* __restrict__ x,             // [N,128] fp32
    const unsigned short* __restrict__ wtb,  // [n:128][k:128] bf16 (B^T layout)
    const float* __restrict__ att_src, const float* __restrict__ att_dst,
    unsigned short* __restrict__ hb,         // [N,128] bf16
    float* __restrict__ a_src, float* __restrict__ a_dst)
{
    const int wave = threadIdx.x >> 6;
    const int lane = threadIdx.x & 63;
    const int n0   = (wave & 1) * 64;        // n-strip per wave
    const int l15  = lane & 15;
    const int quad = lane >> 4;

    // B frags, loaded once: B[k=ks*32+quad*8+j][n=n0+16t+l15] = Wt[n][k]
    short8 bfrag[4][4];
    #pragma unroll
    for (int t = 0; t < 4; ++t)
        #pragma unroll
        for (int ks = 0; ks < 4; ++ks)
            bfrag[t][ks] = *(const short8*)&wtb[(n0 + t * 16 + l15) * 128 + ks * 32 + quad * 8];

    // att weights for my 4 columns (col = n0 + t*16 + l15)
    float asw[4], adw[4];
    #pragma unroll
    for (int t = 0; t < 4; ++t) {
        asw[t] = att_src[n0 + t * 16 + l15];
        adw[t] = att_dst[n0 + t * 16 + l15];
    }

    for (int mt = blockIdx.x * 2 + (wave >> 1); mt < M_TILES; mt += gridDim.x * 2) {
        const int m0 = mt * 16;
        short8 afrag[4];                     // A[m=m0+l15][k=ks*32+quad*8+j]
        #pragma unroll
        for (int ks = 0; ks < 4; ++ks) {
            const float4 u0 = *(const float4*)&x[(size_t)(m0 + l15) * 128 + ks * 32 + quad * 8];
            const float4 u1 = *(const float4*)&x[(size_t)(m0 + l15) * 128 + ks * 32 + quad * 8 + 4];
            short8 a;
            a[0] = (short)f2bf(u0.x); a[1] = (short)f2bf(u0.y);
            a[2] = (short)f2bf(u0.z); a[3] = (short)f2bf(u0.w);
            a[4] = (short)f2bf(u1.x); a[5] = (short)f2bf(u1.y);
            a[6] = (short)f2bf(u1.z); a[7] = (short)f2bf(u1.w);
            afrag[ks] = a;
        }

        f32x4 acc[4];
        #pragma unroll
        for (int t = 0; t < 4; ++t) acc[t] = (f32x4){0.f, 0.f, 0.f, 0.f};

        #pragma unroll
        for (int ks = 0; ks < 4; ++ks)
            #pragma unroll
            for (int t = 0; t < 4; ++t)
                acc[t] = __builtin_amdgcn_mfma_f32_16x16x32_bf16(afrag[ks], bfrag[t][ks], acc[t], 0, 0, 0);

        // C/D: row = m0 + quad*4 + r, col = n0 + t*16 + l15
        #pragma unroll
        for (int t = 0; t < 4; ++t)
            #pragma unroll
            for (int r = 0; r < 4; ++r)
                hb[(m0 + quad * 4 + r) * 128 + n0 + t * 16 + l15] = f2bf(acc[t][r]);

        // fused attention dots: per lane, head g = n0/32 + (t>>1)
        float hs[2][4] = {{0.f,0.f,0.f,0.f},{0.f,0.f,0.f,0.f}};
        float hd[2][4] = {{0.f,0.f,0.f,0.f},{0.f,0.f,0.f,0.f}};
        #pragma unroll
        for (int t = 0; t < 4; ++t)
            #pragma unroll
            for (int r = 0; r < 4; ++r) {
                hs[t >> 1][r] += acc[t][r] * asw[t];
                hd[t >> 1][r] += acc[t][r] * adw[t];
            }
        #pragma unroll
        for (int off = 1; off < 16; off <<= 1)
            #pragma unroll
            for (int g = 0; g < 2; ++g)
                #pragma unroll
                for (int r = 0; r < 4; ++r) {
                    hs[g][r] += __shfl_xor(hs[g][r], off);
                    hd[g][r] += __shfl_xor(hd[g][r], off);
                }
        if (l15 == 0) {
            const int hb0 = n0 >> 5;         // first head of this strip
            #pragma unroll
            for (int g = 0; g < 2; ++g)
                #pragma unroll
                for (int r = 0; r < 4; ++r) {
                    a_src[(m0 + quad * 4 + r) * 4 + hb0 + g] = hs[g][r];
                    a_dst[(m0 + quad * 4 + r) * 4 + hb0 + g] = hd[g][r];
                }
        }
    }
}

// ---------------- aggregation: wave per dst node, 2 edges in flight --------

__global__ __launch_bounds__(256) void gat_agg(
    const int* __restrict__ row_start, const int* __restrict__ csr_src,
    const unsigned short* __restrict__ hb, const float* __restrict__ a_src,
    const float* __restrict__ a_dst, const float* __restrict__ bias,
    float* __restrict__ out)
{
    __shared__ float ws[4][256];             // [wave][edge*4 + head]
    const int wv = threadIdx.x >> 6;
    const int node = blockIdx.x * 4 + wv;
    if (node >= N_NODES) return;
    const int lane = threadIdx.x & 63;
    const int half = lane >> 5;              // which edge of the pair
    const int li   = lane & 31;
    const int ch0  = li * 4;                 // 4 channels per lane
    const int hd   = li >> 3;                // head of my channels
    const float4 ad4 = *(const float4*)&a_dst[node * 4];
    const int p0 = row_start[node], p1 = row_start[node + 1];

    float acc0 = 0.f, acc1 = 0.f, acc2 = 0.f, acc3 = 0.f, dsum = 0.f;

    for (int base = p0; base < p1; base += 64) {
        int m = p1 - base; if (m > 64) m = 64;
        int sv = 0;
        if (lane < m) {
            sv = csr_src[base + lane];       // coalesced batch of src ids
            const float4 av = *(const float4*)&a_src[sv * 4];
            float t; float4 w4;
            t = av.x + ad4.x; t = t > 0.f ? t : NEG_SLOPE * t; w4.x = __expf(t);
            t = av.y + ad4.y; t = t > 0.f ? t : NEG_SLOPE * t; w4.y = __expf(t);
            t = av.z + ad4.z; t = t > 0.f ? t : NEG_SLOPE * t; w4.z = __expf(t);
            t = av.w + ad4.w; t = t > 0.f ? t : NEG_SLOPE * t; w4.w = __expf(t);
            *(float4*)&ws[wv][lane * 4] = w4; // all 4 head weights for my edge
        }
        // same-wave LDS RAW: lockstep + compiler lgkmcnt, no barrier needed
        #pragma unroll 2
        for (int j = 0; j < m; j += 2) {
            const int ei  = j + half;        // half0 -> edge j, half1 -> j+1
            const int idx = ei < m ? ei : j;
            const int s   = __shfl(sv, idx);
            float w = ws[wv][idx * 4 + hd];
            if (ei >= m) w = 0.f;
            const uint2 hv = *(const uint2*)&hb[(size_t)s * 128 + ch0];
            const float f0 = __uint_as_float(hv.x << 16);
            const float f1 = __uint_as_float(hv.x & 0xFFFF0000u);
            const float f2 = __uint_as_float(hv.y << 16);
            const float f3 = __uint_as_float(hv.y & 0xFFFF0000u);
            acc0 += w * f0; acc1 += w * f1;
            acc2 += w * f2; acc3 += w * f3;
            dsum += w;
        }
    }
    // combine the two halves (disjoint edge subsets, same channels)
    acc0 += __shfl_xor(acc0, 32); acc1 += __shfl_xor(acc1, 32);
    acc2 += __shfl_xor(acc2, 32); acc3 += __shfl_xor(acc3, 32);
    dsum += __shfl_xor(dsum, 32);
    if (half == 0) {
        const float inv = 1.f / dsum;        // dsum >= exp(self) > 0
        const float4 b4 = *(const float4*)&bias[ch0];
        float4 o;
        o.x = acc0 * inv + b4.x; o.y = acc1 * inv + b4.y;
        o.z = acc2 * inv + b4.z; o.w = acc3 * inv + b4.w;
        *(float4*)&out[(size_t)node * HC + ch0] = o;
    }
}

extern "C" void kernel_launch(void* const* d_in, const int* in_sizes, int n_in,
                              void* d_out, int out_size, void* d_ws, size_t ws_size,
                              hipStream_t stream) {
    const float* x       = (const float*)d_in[0];
    const int*   ei      = (const int*)  d_in[1];   // [2,E]: row0=src, row1=dst
    const float* W       = (const float*)d_in[2];
    const float* att_src = (const float*)d_in[3];
    const float* att_dst = (const float*)d_in[4];
    const float* bias    = (const float*)d_in[5];
    float* out = (float*)d_out;

    // ws layout (~22 MB): hb | wtb | a_src | a_dst | csr_src | row_st | deg | ppos | bsum
    char* p = (char*)d_ws;
    unsigned short* hb  = (unsigned short*)p; p += (size_t)N_NODES * HC * 2;  // 12.8 MB
    unsigned short* wtb = (unsigned short*)p; p += 128 * 128 * 2;             // 32 KB
    float* a_src = (float*)p; p += (size_t)N_NODES * 4 * 4;                   // 800 KB
    float* a_dst = (float*)p; p += (size_t)N_NODES * 4 * 4;
    int* csr_src = (int*)p;   p += (size_t)E_TOT * 4;                         // 3.4 MB
    int* row_st  = (int*)p;   p += (N_NODES + 4) * 4;
    int* deg     = (int*)p;   p += N_NODES * 4;
    int* ppos    = (int*)p;   p += (size_t)N_EDGES * 4;                       // 3.2 MB
    int* bsum    = (int*)p;

    const int* esrc = ei;
    const int* edst = ei + N_EDGES;

    hipMemsetAsync(deg, 0, (size_t)N_NODES * sizeof(int), stream);

    hist       <<<(N_EDGES + 255) / 256, 256, 0, stream>>>(edst, deg, ppos);
    scan_blocks<<<SCAN_BLOCKS, 256, 0, stream>>>(deg, row_st, bsum);
    scan_bsum  <<<1, 256, 0, stream>>>(bsum);
    scan_add   <<<SCAN_BLOCKS, 256, 0, stream>>>(row_st, bsum, csr_src);
    scatter    <<<(N_EDGES + 255) / 256, 256, 0, stream>>>(esrc, edst, row_st, ppos, csr_src);

    cast_w     <<<64, 256, 0, stream>>>(W, wtb);
    gat_gemm   <<<512, 256, 0, stream>>>(x, wtb, att_src, att_dst, hb, a_src, a_dst);
    gat_agg    <<<(N_NODES + 3) / 4, 256, 0, stream>>>(row_st, csr_src, hb, a_src, a_dst, bias, out);
}

// Round 5
// 174.014 us; speedup vs baseline: 3.9304x; 1.1431x over previous
//
#include <hip/hip_runtime.h>

// GATConv single layer. N=50000, E=800000 (+N self loops), IN=128, H*C=128.
//
// R5: fused gemm+hist (independent work overlapped in one dispatch), 2-kernel
// scan (1024-thr blocks + wave-scan), scan_add+scatter merged, agg with 4
// edges in flight (quarter-wave per edge, uint4 h loads).
// Pipeline (all on `stream`):
//   memset deg
//   K1 gemm_hist : blocks[0,512)  h_bf16 = x@W via v_mfma_f32_16x16x32_bf16
//                  (x and W converted in-register; fused a_src/a_dst epilogue)
//                  blocks[512,1024) ppos[e] = deg[dst]++  (grid-stride)
//   K2 scan_blocks: per-1024-block exclusive scan of (deg+1) -> partial, bsum
//   K3 scan_bsum  : wave64 exclusive scan of 49 block sums
//   K4 scatter_fin: edges: csr_src[partial[d]+bsum[d>>10] + 1 + ppos[e]] = src
//                   nodes: row_st[i] = final offset; csr_src[row_st[i]] = i
//   K5 gat_agg    : wave per dst node; 64-edge coalesced batches; one lane per
//                   edge computes all 4 head weights (4 exp) into LDS; four
//                   quarter-waves process 4 edges in flight, 8 ch/lane uint4;
//                   denom in-register; fused /denom + bias, float4 stores.
// No segment-max: logits are O(7), exp() safe in fp32; exp(e)/sum == softmax.

constexpr int N_NODES = 50000;
constexpr int N_EDGES = 800000;
constexpr int E_TOT   = N_EDGES + N_NODES;  // 850000
constexpr int HC      = 128;
constexpr float NEG_SLOPE = 0.2f;
constexpr int M_TILES = N_NODES / 16;               // 3125
constexpr int NB_GEMM = 512;
constexpr int NB_HIST = 512;
constexpr int SCAN_BLOCKS = (N_NODES + 1023) / 1024;  // 49

typedef short short8 __attribute__((ext_vector_type(8)));
typedef float f32x4  __attribute__((ext_vector_type(4)));

__device__ inline unsigned short f2bf(float f) {   // RTNE
    unsigned int u = __float_as_uint(f);
    u += 0x7FFF + ((u >> 16) & 1);
    return (unsigned short)(u >> 16);
}

// ---- K1: fused MFMA GEMM (+attention-dot epilogue) and edge histogram ----

__global__ __launch_bounds__(256) void gemm_hist(
    const float* __restrict__ x,             // [N,128] fp32
    const float* __restrict__ W,             // [k:128][n:128] fp32
    const float* __restrict__ att_src, const float* __restrict__ att_dst,
    const int* __restrict__ edst,
    unsigned short* __restrict__ hb,         // [N,128] bf16
    float* __restrict__ a_src, float* __restrict__ a_dst,
    int* __restrict__ deg, int* __restrict__ ppos)
{
    if (blockIdx.x >= NB_GEMM) {
        // ---------------- histogram part ----------------
        const int t0 = (blockIdx.x - NB_GEMM) * 256 + threadIdx.x;
        for (int e = t0; e < N_EDGES; e += NB_HIST * 256)
            ppos[e] = atomicAdd(&deg[edst[e]], 1);
        return;
    }
    // ---------------- GEMM part ----------------
    const int wave = threadIdx.x >> 6;
    const int lane = threadIdx.x & 63;
    const int n0   = (wave & 1) * 64;        // n-strip per wave
    const int l15  = lane & 15;
    const int quad = lane >> 4;

    // B frags direct from fp32 W (L2-resident, once per block):
    // B[k=ks*32+quad*8+j][n=n0+16t+l15] = W[k*128+n]
    short8 bfrag[4][4];
    #pragma unroll
    for (int t = 0; t < 4; ++t)
        #pragma unroll
        for (int ks = 0; ks < 4; ++ks) {
            short8 b;
            #pragma unroll
            for (int j = 0; j < 8; ++j)
                b[j] = (short)f2bf(W[(ks * 32 + quad * 8 + j) * 128 + n0 + t * 16 + l15]);
            bfrag[t][ks] = b;
        }

    // att weights for my 4 columns (col = n0 + t*16 + l15)
    float asw[4], adw[4];
    #pragma unroll
    for (int t = 0; t < 4; ++t) {
        asw[t] = att_src[n0 + t * 16 + l15];
        adw[t] = att_dst[n0 + t * 16 + l15];
    }

    for (int mt = blockIdx.x * 2 + (wave >> 1); mt < M_TILES; mt += NB_GEMM * 2) {
        const int m0 = mt * 16;
        short8 afrag[4];                     // A[m=m0+l15][k=ks*32+quad*8+j]
        #pragma unroll
        for (int ks = 0; ks < 4; ++ks) {
            const float4 u0 = *(const float4*)&x[(size_t)(m0 + l15) * 128 + ks * 32 + quad * 8];
            const float4 u1 = *(const float4*)&x[(size_t)(m0 + l15) * 128 + ks * 32 + quad * 8 + 4];
            short8 a;
            a[0] = (short)f2bf(u0.x); a[1] = (short)f2bf(u0.y);
            a[2] = (short)f2bf(u0.z); a[3] = (short)f2bf(u0.w);
            a[4] = (short)f2bf(u1.x); a[5] = (short)f2bf(u1.y);
            a[6] = (short)f2bf(u1.z); a[7] = (short)f2bf(u1.w);
            afrag[ks] = a;
        }

        f32x4 acc[4];
        #pragma unroll
        for (int t = 0; t < 4; ++t) acc[t] = (f32x4){0.f, 0.f, 0.f, 0.f};

        #pragma unroll
        for (int ks = 0; ks < 4; ++ks)
            #pragma unroll
            for (int t = 0; t < 4; ++t)
                acc[t] = __builtin_amdgcn_mfma_f32_16x16x32_bf16(afrag[ks], bfrag[t][ks], acc[t], 0, 0, 0);

        // C/D: row = m0 + quad*4 + r, col = n0 + t*16 + l15
        #pragma unroll
        for (int t = 0; t < 4; ++t)
            #pragma unroll
            for (int r = 0; r < 4; ++r)
                hb[(m0 + quad * 4 + r) * 128 + n0 + t * 16 + l15] = f2bf(acc[t][r]);

        // fused attention dots: per lane, head g = n0/32 + (t>>1)
        float hs[2][4] = {{0.f,0.f,0.f,0.f},{0.f,0.f,0.f,0.f}};
        float hd[2][4] = {{0.f,0.f,0.f,0.f},{0.f,0.f,0.f,0.f}};
        #pragma unroll
        for (int t = 0; t < 4; ++t)
            #pragma unroll
            for (int r = 0; r < 4; ++r) {
                hs[t >> 1][r] += acc[t][r] * asw[t];
                hd[t >> 1][r] += acc[t][r] * adw[t];
            }
        #pragma unroll
        for (int off = 1; off < 16; off <<= 1)
            #pragma unroll
            for (int g = 0; g < 2; ++g)
                #pragma unroll
                for (int r = 0; r < 4; ++r) {
                    hs[g][r] += __shfl_xor(hs[g][r], off);
                    hd[g][r] += __shfl_xor(hd[g][r], off);
                }
        if (l15 == 0) {
            const int hb0 = n0 >> 5;         // first head of this strip
            #pragma unroll
            for (int g = 0; g < 2; ++g)
                #pragma unroll
                for (int r = 0; r < 4; ++r) {
                    a_src[(m0 + quad * 4 + r) * 4 + hb0 + g] = hs[g][r];
                    a_dst[(m0 + quad * 4 + r) * 4 + hb0 + g] = hd[g][r];
                }
        }
    }
}

// ---------------- scan ----------------

__global__ __launch_bounds__(1024) void scan_blocks(const int* __restrict__ deg,
                                                    int* __restrict__ partial,
                                                    int* __restrict__ bsum) {
    __shared__ int sm[1024];
    const int tid = threadIdx.x;
    const int i = blockIdx.x * 1024 + tid;
    const int v = (i < N_NODES) ? deg[i] + 1 : 0;    // +1 = self loop
    sm[tid] = v; __syncthreads();
    for (int off = 1; off < 1024; off <<= 1) {
        const int t = (tid >= off) ? sm[tid - off] : 0;
        __syncthreads();
        sm[tid] += t;
        __syncthreads();
    }
    if (i < N_NODES) partial[i] = sm[tid] - v;
    if (tid == 1023) bsum[blockIdx.x] = sm[1023];
}

__global__ __launch_bounds__(64) void scan_bsum(int* __restrict__ bsum) {
    const int tid = threadIdx.x;
    const int v = (tid < SCAN_BLOCKS) ? bsum[tid] : 0;
    int s = v;
    #pragma unroll
    for (int off = 1; off < 64; off <<= 1) {
        const int t = __shfl_up(s, off);
        if (tid >= off) s += t;
    }
    if (tid < SCAN_BLOCKS) bsum[tid] = s - v;        // exclusive
}

// ---- K4: scatter edges + finalize row_start + plant self loops ----

__global__ __launch_bounds__(256) void scatter_fin(
    const int* __restrict__ esrc, const int* __restrict__ edst,
    const int* __restrict__ partial, const int* __restrict__ bsum,
    const int* __restrict__ ppos,
    int* __restrict__ row_st, int* __restrict__ csr_src)
{
    const int idx = blockIdx.x * 256 + threadIdx.x;
    if (idx < N_EDGES) {
        const int d = edst[idx];
        const int pos = partial[d] + bsum[d >> 10] + 1 + ppos[idx];
        csr_src[pos] = esrc[idx];
    } else if (idx < E_TOT) {
        const int i = idx - N_EDGES;                 // node domain
        const int r = partial[i] + bsum[i >> 10];
        row_st[i] = r;
        csr_src[r] = i;                              // self loop in slot 0
        if (i == 0) row_st[N_NODES] = E_TOT;
    }
}

// ---- K5: aggregation — wave per dst node, 4 edges in flight ----

__global__ __launch_bounds__(256) void gat_agg(
    const int* __restrict__ row_start, const int* __restrict__ csr_src,
    const unsigned short* __restrict__ hb, const float* __restrict__ a_src,
    const float* __restrict__ a_dst, const float* __restrict__ bias,
    float* __restrict__ out)
{
    __shared__ float ws[4][256];             // [wave][edge*4 + head]
    const int wv = threadIdx.x >> 6;
    const int node = blockIdx.x * 4 + wv;
    if (node >= N_NODES) return;
    const int lane = threadIdx.x & 63;
    const int q    = lane >> 4;              // quarter: which edge of the 4
    const int li   = lane & 15;
    const int ch0  = li * 8;                 // 8 channels per lane
    const int hd   = li >> 2;                // head of my channels (ch0/32)
    const float4 ad4 = *(const float4*)&a_dst[node * 4];
    const int p0 = row_start[node], p1 = row_start[node + 1];

    float acc[8] = {0.f,0.f,0.f,0.f,0.f,0.f,0.f,0.f};
    float dsum = 0.f;

    for (int base = p0; base < p1; base += 64) {
        int m = p1 - base; if (m > 64) m = 64;
        int sv = 0;
        if (lane < m) {
            sv = csr_src[base + lane];       // coalesced batch of src ids
            const float4 av = *(const float4*)&a_src[sv * 4];
            float t; float4 w4;
            t = av.x + ad4.x; t = t > 0.f ? t : NEG_SLOPE * t; w4.x = __expf(t);
            t = av.y + ad4.y; t = t > 0.f ? t : NEG_SLOPE * t; w4.y = __expf(t);
            t = av.z + ad4.z; t = t > 0.f ? t : NEG_SLOPE * t; w4.z = __expf(t);
            t = av.w + ad4.w; t = t > 0.f ? t : NEG_SLOPE * t; w4.w = __expf(t);
            *(float4*)&ws[wv][lane * 4] = w4; // all 4 head weights for my edge
        }
        // same-wave LDS RAW: lockstep + compiler lgkmcnt, no barrier needed
        for (int j = 0; j < m; j += 4) {
            const int ei  = j + q;           // quarter q -> edge j+q
            const int idx = ei < m ? ei : j;
            const int s   = __shfl(sv, idx);
            float w = ws[wv][idx * 4 + hd];
            if (ei >= m) w = 0.f;
            const uint4 hv = *(const uint4*)&hb[(size_t)s * 128 + ch0];
            acc[0] += w * __uint_as_float(hv.x << 16);
            acc[1] += w * __uint_as_float(hv.x & 0xFFFF0000u);
            acc[2] += w * __uint_as_float(hv.y << 16);
            acc[3] += w * __uint_as_float(hv.y & 0xFFFF0000u);
            acc[4] += w * __uint_as_float(hv.z << 16);
            acc[5] += w * __uint_as_float(hv.z & 0xFFFF0000u);
            acc[6] += w * __uint_as_float(hv.w << 16);
            acc[7] += w * __uint_as_float(hv.w & 0xFFFF0000u);
            dsum += w;
        }
    }
    // combine the four quarters (disjoint edge subsets, same channels)
    #pragma unroll
    for (int off = 16; off <= 32; off <<= 1) {
        #pragma unroll
        for (int r = 0; r < 8; ++r) acc[r] += __shfl_xor(acc[r], off);
        dsum += __shfl_xor(dsum, off);
    }
    if (q == 0) {
        const float inv = 1.f / dsum;        // dsum >= exp(self) > 0
        const float4 b0 = *(const float4*)&bias[ch0];
        const float4 b1 = *(const float4*)&bias[ch0 + 4];
        float4 o0, o1;
        o0.x = acc[0]*inv + b0.x; o0.y = acc[1]*inv + b0.y;
        o0.z = acc[2]*inv + b0.z; o0.w = acc[3]*inv + b0.w;
        o1.x = acc[4]*inv + b1.x; o1.y = acc[5]*inv + b1.y;
        o1.z = acc[6]*inv + b1.z; o1.w = acc[7]*inv + b1.w;
        *(float4*)&out[(size_t)node * HC + ch0]     = o0;
        *(float4*)&out[(size_t)node * HC + ch0 + 4] = o1;
    }
}

extern "C" void kernel_launch(void* const* d_in, const int* in_sizes, int n_in,
                              void* d_out, int out_size, void* d_ws, size_t ws_size,
                              hipStream_t stream) {
    const float* x       = (const float*)d_in[0];
    const int*   ei      = (const int*)  d_in[1];   // [2,E]: row0=src, row1=dst
    const float* W       = (const float*)d_in[2];
    const float* att_src = (const float*)d_in[3];
    const float* att_dst = (const float*)d_in[4];
    const float* bias    = (const float*)d_in[5];
    float* out = (float*)d_out;

    // ws layout (~21.6 MB): hb | a_src | a_dst | csr_src | partial | row_st | deg | ppos | bsum
    char* p = (char*)d_ws;
    unsigned short* hb  = (unsigned short*)p; p += (size_t)N_NODES * HC * 2;  // 12.8 MB
    float* a_src = (float*)p; p += (size_t)N_NODES * 4 * 4;                   // 800 KB
    float* a_dst = (float*)p; p += (size_t)N_NODES * 4 * 4;
    int* csr_src = (int*)p;   p += (size_t)E_TOT * 4;                         // 3.4 MB
    int* partial = (int*)p;   p += N_NODES * 4;
    int* row_st  = (int*)p;   p += (N_NODES + 4) * 4;
    int* deg     = (int*)p;   p += N_NODES * 4;
    int* ppos    = (int*)p;   p += (size_t)N_EDGES * 4;                       // 3.2 MB
    int* bsum    = (int*)p;

    const int* esrc = ei;
    const int* edst = ei + N_EDGES;

    hipMemsetAsync(deg, 0, (size_t)N_NODES * sizeof(int), stream);

    gemm_hist  <<<NB_GEMM + NB_HIST, 256, 0, stream>>>(x, W, att_src, att_dst,
                                                       edst, hb, a_src, a_dst, deg, ppos);
    scan_blocks<<<SCAN_BLOCKS, 1024, 0, stream>>>(deg, partial, bsum);
    scan_bsum  <<<1, 64, 0, stream>>>(bsum);
    scatter_fin<<<(E_TOT + 255) / 256, 256, 0, stream>>>(esrc, edst, partial, bsum,
                                                         ppos, row_st, csr_src);
    gat_agg    <<<(N_NODES + 3) / 4, 256, 0, stream>>>(row_st, csr_src, hb, a_src,
                                                       a_dst, bias, out);
}